// Round 2
// baseline (857.840 us; speedup 1.0000x reference)
//
#include <hip/hip_runtime.h>
#include <math.h>

#define NB_B 16
#define NB_S 4096
#define NB_D 64
#define NB_H 8

__device__ __forceinline__ float f4c(const float4& v, int k) {
  return k == 0 ? v.x : k == 1 ? v.y : k == 2 ? v.z : v.w;
}

// ---------------- Kernel 1: LSH hashing (buckets) ----------------
// Bit-faithful mimic of naive np.einsum float32: for each (token, i),
// acc over f ascending, round(mul) then round(add), NO fma, then
// first-occurrence argmax over [acc, -acc]. One thread per token.
// grid: B*H*16 blocks (256 tokens per block), 256 threads
__global__ __launch_bounds__(256) void hash_kernel(const float* __restrict__ qk,
                                                   const float* __restrict__ rot,
                                                   int* __restrict__ bkt) {
  __shared__ float rotS[64 * 32];  // [f][i]
  int tid = threadIdx.x;
  int blk = blockIdx.x;
  int tile = blk & 15, bh = blk >> 4;
  int h = bh & 7, b = bh >> 3;
  int t = (tile << 8) + tid;

  for (int i = tid; i < 2048; i += 256) {
    int f = i >> 5, ii = i & 31;
    rotS[i] = rot[(((size_t)b * 64 + f) * 8 + h) * 32 + ii];
  }
  __syncthreads();

  const float4* qrow = (const float4*)(qk + (((size_t)b << 12) + t) * 64);
  float qreg[64];
#pragma unroll
  for (int j = 0; j < 16; j++) *(float4*)(qreg + 4 * j) = qrow[j];

  float acc[32];
#pragma unroll
  for (int i = 0; i < 32; i++) acc[i] = 0.f;

#pragma unroll
  for (int f = 0; f < 64; f++) {
    float qf = qreg[f];
#pragma unroll
    for (int i4 = 0; i4 < 8; i4++) {
      float4 w = *(const float4*)(rotS + f * 32 + i4 * 4);
      acc[i4 * 4 + 0] = __fadd_rn(acc[i4 * 4 + 0], __fmul_rn(qf, w.x));
      acc[i4 * 4 + 1] = __fadd_rn(acc[i4 * 4 + 1], __fmul_rn(qf, w.y));
      acc[i4 * 4 + 2] = __fadd_rn(acc[i4 * 4 + 2], __fmul_rn(qf, w.z));
      acc[i4 * 4 + 3] = __fadd_rn(acc[i4 * 4 + 3], __fmul_rn(qf, w.w));
    }
  }

  // argmax over concat([acc, -acc]); strict > keeps first occurrence,
  // positives (indices 0..31) precede negatives (32..63), matching np.
  float b1 = acc[0];
  int i1 = 0;
#pragma unroll
  for (int i = 1; i < 32; i++)
    if (acc[i] > b1) { b1 = acc[i]; i1 = i; }
#pragma unroll
  for (int i = 0; i < 32; i++) {
    float x = -acc[i];
    if (x > b1) { b1 = x; i1 = 32 + i; }
  }
  bkt[(((size_t)(b * 8 + h)) << 12) + t] = i1;
}

// ---------------- Kernel 2: stable counting sort per (b,h) ----------------
// grid: B*H blocks, 256 threads
__global__ __launch_bounds__(256) void sort_kernel(const int* __restrict__ bkt,
                                                   int* __restrict__ st) {
  __shared__ int lb[4096];
  __shared__ int hist[4096];  // [chunk(64)][bucket(64)]
  __shared__ int cumoff[64];
  __shared__ int tot[64];
  int tid = threadIdx.x;
  int b = blockIdx.x >> 3, h = blockIdx.x & 7;
  const int* gb = bkt + (((size_t)(b * 8 + h)) << 12);
  for (int t = tid; t < 4096; t += 256) lb[t] = gb[t];
  for (int i = tid; i < 4096; i += 256) hist[i] = 0;
  __syncthreads();
  for (int t = tid; t < 4096; t += 256) atomicAdd(&hist[((t >> 6) << 6) | lb[t]], 1);
  __syncthreads();
  if (tid < 64) {
    int run = 0;
    for (int cc = 0; cc < 64; cc++) {
      int x = hist[(cc << 6) | tid];
      hist[(cc << 6) | tid] = run;
      run += x;
    }
    tot[tid] = run;
  }
  __syncthreads();
  if (tid == 0) {
    int run = 0;
    for (int vb = 0; vb < 64; vb++) { cumoff[vb] = run; run += tot[vb]; }
  }
  __syncthreads();
  int lane = tid & 63;
  for (int p = 0; p < 16; p++) {
    int t = (p << 8) + tid;  // each wave covers one aligned 64-token chunk
    int vb = lb[t];
    unsigned long long m = 0xFFFFFFFFFFFFFFFFull;
#pragma unroll
    for (int bit = 0; bit < 6; bit++) {
      unsigned long long bl = __ballot((vb >> bit) & 1);
      m &= ((vb >> bit) & 1) ? bl : ~bl;
    }
    int rank = __popcll(m & ((1ull << lane) - 1ull));
    int cpos = cumoff[vb] + hist[((t >> 6) << 6) | vb] + rank;
    st[(((size_t)(b * 8 + h)) << 12) + cpos] = t;
  }
}

// ---------------- Kernel 3: pass A — per-row logsumexp ----------------
// grid: B*512 blocks (one 64q x 128k chunk each), 256 threads
__global__ __launch_bounds__(256) void passA_kernel(const float* __restrict__ qk,
                                                    const int* __restrict__ st,
                                                    float* __restrict__ lse) {
  __shared__ float Qs[64 * 68];
  __shared__ float Ks[128 * 68];
  __shared__ int tq[64];
  __shared__ int tk[128];
  int tid = threadIdx.x;
  int g = blockIdx.x & 511;
  int b = blockIdx.x >> 9;
  int h = g >> 6, c = g & 63;
  int gp = (g + 511) & 511;
  int hp = gp >> 6, cp = gp & 63;
  if (tid < 64) {
    int t = st[(((size_t)(b * 8 + h)) << 12) + (c << 6) + tid];
    tq[tid] = t;
    tk[tid] = t;
  } else if (tid < 128) {
    int j = tid - 64;
    tk[64 + j] = st[(((size_t)(b * 8 + hp)) << 12) + (cp << 6) + j];
  }
  __syncthreads();
  for (int idx = tid; idx < 192 * 16; idx += 256) {
    int row = idx >> 4, fo = idx & 15;
    if (row < 64) {
      ((float4*)(Qs + row * 68))[fo] =
          ((const float4*)(qk + (((size_t)b << 12) + tq[row]) * 64))[fo];
    } else {
      int r = row - 64;
      ((float4*)(Ks + r * 68))[fo] =
          ((const float4*)(qk + (((size_t)b << 12) + tk[r]) * 64))[fo];
    }
  }
  __syncthreads();
  if (tid < 128) {
    float ss = 0.f;
    for (int d2 = 0; d2 < 64; d2++) { float x = Ks[tid * 68 + d2]; ss += x * x; }
    float sc = 1.0f / fmaxf(sqrtf(ss), 1e-12f);
    for (int d2 = 0; d2 < 64; d2++) Ks[tid * 68 + d2] *= sc;
  }
  __syncthreads();

  int tr = tid >> 4, tc = tid & 15;  // rows 4*tr.., cols tc+16j
  float acc[4][8];
#pragma unroll
  for (int r = 0; r < 4; r++)
#pragma unroll
    for (int j = 0; j < 8; j++) acc[r][j] = 0.f;

  for (int d = 0; d < 64; d += 4) {
    float4 a[4];
#pragma unroll
    for (int r = 0; r < 4; r++) a[r] = *(const float4*)(Qs + (tr * 4 + r) * 68 + d);
    float4 bk[8];
#pragma unroll
    for (int j = 0; j < 8; j++) bk[j] = *(const float4*)(Ks + (tc + j * 16) * 68 + d);
#pragma unroll
    for (int r = 0; r < 4; r++) {
#pragma unroll
      for (int j = 0; j < 8; j++) {
        acc[r][j] += a[r].x * bk[j].x;
        acc[r][j] += a[r].y * bk[j].y;
        acc[r][j] += a[r].z * bk[j].z;
        acc[r][j] += a[r].w * bk[j].w;
      }
    }
  }

#pragma unroll
  for (int r = 0; r < 4; r++) {
    int ti = tq[tr * 4 + r];
    float vv[8];
    float m = -3.4e38f;
#pragma unroll
    for (int j = 0; j < 8; j++) {
      int tjn = tk[tc + j * 16];
      float val = (ti == tjn) ? -50000.0f : acc[r][j] * 0.125f;
      vv[j] = val;
      m = fmaxf(m, val);
    }
    for (int off = 1; off < 16; off <<= 1) m = fmaxf(m, __shfl_xor(m, off));
    float ssum = 0.f;
#pragma unroll
    for (int j = 0; j < 8; j++) ssum += expf(vv[j] - m);
    for (int off = 1; off < 16; off <<= 1) ssum += __shfl_xor(ssum, off);
    if (tc == 0) lse[(((size_t)(b * 8 + h)) << 12) + ti] = m + logf(ssum);
  }
}

// ---------------- Kernel 4: logsumexp across hash rounds ----------------
__global__ __launch_bounds__(256) void lsetot_kernel(const float* __restrict__ lse,
                                                     float* __restrict__ lset) {
  int idx = blockIdx.x * 256 + threadIdx.x;  // over B*S
  int b = idx >> 12, t = idx & 4095;
  float vals[8];
  float m = -3.4e38f;
#pragma unroll
  for (int hh = 0; hh < 8; hh++) {
    vals[hh] = lse[(((size_t)(b * 8 + hh)) << 12) + t];
    m = fmaxf(m, vals[hh]);
  }
  float ssum = 0.f;
#pragma unroll
  for (int hh = 0; hh < 8; hh++) ssum += expf(vals[hh] - m);
  lset[idx] = m + logf(ssum);
}

// ---------------- Kernel 5: pass B — weighted PV, scatter-add ----------------
// grid: B*512 blocks, 256 threads
__global__ __launch_bounds__(256) void passB_kernel(const float* __restrict__ qk,
                                                    const float* __restrict__ vv,
                                                    const int* __restrict__ st,
                                                    const float* __restrict__ lset,
                                                    float* __restrict__ out) {
  __shared__ float Ks[64 * 68];
  __shared__ float Vs[64 * 68];
  __shared__ float Ps[64 * 68];
  __shared__ int tq[64];
  __shared__ int tk[128];
  __shared__ float lsetS[64];
  int tid = threadIdx.x;
  int g = blockIdx.x & 511;
  int b = blockIdx.x >> 9;
  int h = g >> 6, c = g & 63;
  int gp = (g + 511) & 511;
  int hp = gp >> 6, cp = gp & 63;
  if (tid < 64) {
    int t = st[(((size_t)(b * 8 + h)) << 12) + (c << 6) + tid];
    tq[tid] = t;
    tk[tid] = t;
  } else if (tid < 128) {
    int j = tid - 64;
    tk[64 + j] = st[(((size_t)(b * 8 + hp)) << 12) + (cp << 6) + j];
  }
  __syncthreads();
  if (tid < 64) lsetS[tid] = lset[(b << 12) + tq[tid]];

  int tr = tid >> 4, tc = tid & 15;
  const float* qbase = qk + (((size_t)b << 12)) * 64;
  const float4* qrow[4];
#pragma unroll
  for (int r = 0; r < 4; r++) qrow[r] = (const float4*)(qbase + (size_t)tq[tr * 4 + r] * 64);

  float acc2[4][4];
#pragma unroll
  for (int r = 0; r < 4; r++)
#pragma unroll
    for (int cc = 0; cc < 4; cc++) acc2[r][cc] = 0.f;

  for (int half = 0; half < 2; half++) {
    if (half) __syncthreads();  // protect Ps/Vs reads of prev iter
    for (int idx = tid; idx < 64 * 16; idx += 256) {
      int row = idx >> 4, fo = idx & 15;
      int tok = tk[half * 64 + row];
      ((float4*)(Ks + row * 68))[fo] =
          ((const float4*)(qk + (((size_t)b << 12) + tok) * 64))[fo];
      ((float4*)(Vs + row * 68))[fo] =
          ((const float4*)(vv + (((size_t)b << 12) + tok) * 64))[fo];
    }
    __syncthreads();
    if (tid < 64) {
      float ss = 0.f;
      for (int d2 = 0; d2 < 64; d2++) { float x = Ks[tid * 68 + d2]; ss += x * x; }
      float sc = 1.0f / fmaxf(sqrtf(ss), 1e-12f);
      for (int d2 = 0; d2 < 64; d2++) Ks[tid * 68 + d2] *= sc;
    }
    __syncthreads();

    // dots: rows 4*tr.., cols tc+16j (within half)
    float acc[4][4];
#pragma unroll
    for (int r = 0; r < 4; r++)
#pragma unroll
      for (int j = 0; j < 4; j++) acc[r][j] = 0.f;
    for (int d = 0; d < 64; d += 4) {
      float4 a[4];
#pragma unroll
      for (int r = 0; r < 4; r++) a[r] = qrow[r][d >> 2];
      float4 bk[4];
#pragma unroll
      for (int j = 0; j < 4; j++) bk[j] = *(const float4*)(Ks + (tc + j * 16) * 68 + d);
#pragma unroll
      for (int r = 0; r < 4; r++) {
#pragma unroll
        for (int j = 0; j < 4; j++) {
          acc[r][j] += a[r].x * bk[j].x;
          acc[r][j] += a[r].y * bk[j].y;
          acc[r][j] += a[r].z * bk[j].z;
          acc[r][j] += a[r].w * bk[j].w;
        }
      }
    }
#pragma unroll
    for (int r = 0; r < 4; r++) {
      int ti = tq[tr * 4 + r];
      float Lr = lsetS[tr * 4 + r];
#pragma unroll
      for (int j = 0; j < 4; j++) {
        int col = tc + j * 16;
        int tjn = tk[half * 64 + col];
        float pv = (ti == tjn) ? 0.f : expf(acc[r][j] * 0.125f - Lr);
        Ps[(tr * 4 + r) * 68 + col] = pv;
      }
    }
    __syncthreads();
    // PV: rows 4*tr.., dims tc*4..
    for (int j = 0; j < 64; j += 4) {
      float4 pr[4];
#pragma unroll
      for (int r = 0; r < 4; r++) pr[r] = *(const float4*)(Ps + (tr * 4 + r) * 68 + j);
#pragma unroll
      for (int jj = 0; jj < 4; jj++) {
        float4 vr = *(const float4*)(Vs + (j + jj) * 68 + tc * 4);
#pragma unroll
        for (int r = 0; r < 4; r++) {
          float pj = f4c(pr[r], jj);
          acc2[r][0] += pj * vr.x;
          acc2[r][1] += pj * vr.y;
          acc2[r][2] += pj * vr.z;
          acc2[r][3] += pj * vr.w;
        }
      }
    }
  }
#pragma unroll
  for (int r = 0; r < 4; r++) {
    int ti = tq[tr * 4 + r];
    float* dst = out + ((((size_t)b << 12) + ti) << 6) + tc * 4;
    unsafeAtomicAdd(dst + 0, acc2[r][0]);
    unsafeAtomicAdd(dst + 1, acc2[r][1]);
    unsafeAtomicAdd(dst + 2, acc2[r][2]);
    unsafeAtomicAdd(dst + 3, acc2[r][3]);
  }
}

extern "C" void kernel_launch(void* const* d_in, const int* in_sizes, int n_in,
                              void* d_out, int out_size, void* d_ws, size_t ws_size,
                              hipStream_t stream) {
  const float* qk = (const float*)d_in[0];
  const float* v = (const float*)d_in[1];
  const float* rot = (const float*)d_in[2];
  float* out = (float*)d_out;

  int* bkt = (int*)d_ws;                            // B*H*S ints
  int* stp = bkt + NB_B * NB_H * NB_S;              // B*H*S ints
  float* lse = (float*)(stp + NB_B * NB_H * NB_S);  // B*H*S floats
  float* lset = lse + NB_B * NB_H * NB_S;           // B*S floats

  hipMemsetAsync(d_out, 0, (size_t)out_size * sizeof(float), stream);
  hash_kernel<<<NB_B * NB_H * 16, 256, 0, stream>>>(qk, rot, bkt);
  sort_kernel<<<NB_B * NB_H, 256, 0, stream>>>(bkt, stp);
  passA_kernel<<<NB_B * 512, 256, 0, stream>>>(qk, stp, lse);
  lsetot_kernel<<<NB_B * NB_S / 256, 256, 0, stream>>>(lse, lset);
  passB_kernel<<<NB_B * 512, 256, 0, stream>>>(qk, v, stp, lset, out);
}

// Round 3
// 337.945 us; speedup vs baseline: 2.5384x; 2.5384x over previous
//
#include <hip/hip_runtime.h>
#include <math.h>

#define NB_B 16
#define NB_S 4096
#define NB_D 64
#define NB_H 8

typedef _Float16 half_t;
typedef __attribute__((ext_vector_type(2))) _Float16 half2t;
typedef __attribute__((ext_vector_type(4))) _Float16 half4;
typedef __attribute__((ext_vector_type(8))) _Float16 half8;
typedef __attribute__((ext_vector_type(4))) float floatx4;

// ---------------- Kernel 0: precompute fp16 q, k-hat, v ----------------
// grid: B*S*16/256 blocks; thread = (row, d4). 16-lane shuffle for row norm.
__global__ __launch_bounds__(256) void prep_kernel(const float* __restrict__ qk,
                                                   const float* __restrict__ v,
                                                   half_t* __restrict__ qh,
                                                   half_t* __restrict__ khat,
                                                   half_t* __restrict__ vh) {
  int g = blockIdx.x * 256 + threadIdx.x;  // over B*S*16
  float4 qv = ((const float4*)qk)[g];
  float4 vv = ((const float4*)v)[g];
  float ss = qv.x * qv.x + qv.y * qv.y + qv.z * qv.z + qv.w * qv.w;
  for (int off = 1; off < 16; off <<= 1) ss += __shfl_xor(ss, off);
  float sc = 1.0f / fmaxf(sqrtf(ss), 1e-12f);
  half4 hq = {(half_t)qv.x, (half_t)qv.y, (half_t)qv.z, (half_t)qv.w};
  half4 hk = {(half_t)(qv.x * sc), (half_t)(qv.y * sc), (half_t)(qv.z * sc),
              (half_t)(qv.w * sc)};
  half4 hv = {(half_t)vv.x, (half_t)vv.y, (half_t)vv.z, (half_t)vv.w};
  ((half4*)qh)[g] = hq;
  ((half4*)khat)[g] = hk;
  ((half4*)vh)[g] = hv;
}

// ---------------- Kernel 1: LSH hashing (buckets) ----------------
// Bit-faithful mimic of naive np.einsum float32 (keeps bucket decisions
// identical to the harness reference). One thread per token.
__global__ __launch_bounds__(256) void hash_kernel(const float* __restrict__ qk,
                                                   const float* __restrict__ rot,
                                                   int* __restrict__ bkt) {
  __shared__ float rotS[64 * 32];  // [f][i]
  int tid = threadIdx.x;
  int blk = blockIdx.x;
  int tile = blk & 15, bh = blk >> 4;
  int h = bh & 7, b = bh >> 3;
  int t = (tile << 8) + tid;

  for (int i = tid; i < 2048; i += 256) {
    int f = i >> 5, ii = i & 31;
    rotS[i] = rot[(((size_t)b * 64 + f) * 8 + h) * 32 + ii];
  }
  __syncthreads();

  const float4* qrow = (const float4*)(qk + (((size_t)b << 12) + t) * 64);
  float qreg[64];
#pragma unroll
  for (int j = 0; j < 16; j++) *(float4*)(qreg + 4 * j) = qrow[j];

  float acc[32];
#pragma unroll
  for (int i = 0; i < 32; i++) acc[i] = 0.f;

#pragma unroll
  for (int f = 0; f < 64; f++) {
    float qf = qreg[f];
#pragma unroll
    for (int i4 = 0; i4 < 8; i4++) {
      float4 w = *(const float4*)(rotS + f * 32 + i4 * 4);
      acc[i4 * 4 + 0] = __fadd_rn(acc[i4 * 4 + 0], __fmul_rn(qf, w.x));
      acc[i4 * 4 + 1] = __fadd_rn(acc[i4 * 4 + 1], __fmul_rn(qf, w.y));
      acc[i4 * 4 + 2] = __fadd_rn(acc[i4 * 4 + 2], __fmul_rn(qf, w.z));
      acc[i4 * 4 + 3] = __fadd_rn(acc[i4 * 4 + 3], __fmul_rn(qf, w.w));
    }
  }

  float b1 = acc[0];
  int i1 = 0;
#pragma unroll
  for (int i = 1; i < 32; i++)
    if (acc[i] > b1) { b1 = acc[i]; i1 = i; }
#pragma unroll
  for (int i = 0; i < 32; i++) {
    float x = -acc[i];
    if (x > b1) { b1 = x; i1 = 32 + i; }
  }
  bkt[(((size_t)(b * 8 + h)) << 12) + t] = i1;
}

// ---------------- Kernel 2: stable counting sort per (b,h) ----------------
__global__ __launch_bounds__(256) void sort_kernel(const int* __restrict__ bkt,
                                                   int* __restrict__ st) {
  __shared__ int lb[4096];
  __shared__ int hist[4096];  // [chunk(64)][bucket(64)]
  __shared__ int cumoff[64];
  __shared__ int tot[64];
  int tid = threadIdx.x;
  int b = blockIdx.x >> 3, h = blockIdx.x & 7;
  const int* gb = bkt + (((size_t)(b * 8 + h)) << 12);
  for (int t = tid; t < 4096; t += 256) lb[t] = gb[t];
  for (int i = tid; i < 4096; i += 256) hist[i] = 0;
  __syncthreads();
  for (int t = tid; t < 4096; t += 256) atomicAdd(&hist[((t >> 6) << 6) | lb[t]], 1);
  __syncthreads();
  if (tid < 64) {
    int run = 0;
    for (int cc = 0; cc < 64; cc++) {
      int x = hist[(cc << 6) | tid];
      hist[(cc << 6) | tid] = run;
      run += x;
    }
    tot[tid] = run;
  }
  __syncthreads();
  if (tid == 0) {
    int run = 0;
    for (int vb = 0; vb < 64; vb++) { cumoff[vb] = run; run += tot[vb]; }
  }
  __syncthreads();
  int lane = tid & 63;
  for (int p = 0; p < 16; p++) {
    int t = (p << 8) + tid;  // each wave covers one aligned 64-token chunk
    int vb = lb[t];
    unsigned long long m = 0xFFFFFFFFFFFFFFFFull;
#pragma unroll
    for (int bit = 0; bit < 6; bit++) {
      unsigned long long bl = __ballot((vb >> bit) & 1);
      m &= ((vb >> bit) & 1) ? bl : ~bl;
    }
    int rank = __popcll(m & ((1ull << lane) - 1ull));
    int cpos = cumoff[vb] + hist[((t >> 6) << 6) | vb] + rank;
    st[(((size_t)(b * 8 + h)) << 12) + cpos] = t;
  }
}

// ---------------- Kernel 3: pass A — per-row logsumexp (MFMA) ----------------
// grid: B*512 blocks (64q x 128k chunk), 256 threads = 4 waves, 1 M-tile/wave
__global__ __launch_bounds__(256) void passA_kernel(const half_t* __restrict__ qh,
                                                    const half_t* __restrict__ khat,
                                                    const int* __restrict__ st,
                                                    float* __restrict__ lse) {
  __shared__ half_t Qs[64 * 68];
  __shared__ half_t Ks[128 * 68];
  __shared__ int tq[64];
  __shared__ int tk[128];
  int tid = threadIdx.x;
  int g = blockIdx.x & 511;
  int b = blockIdx.x >> 9;
  int h = g >> 6, c = g & 63;
  int gp = (g + 511) & 511;
  int hp = gp >> 6, cp = gp & 63;
  if (tid < 64) {
    int t = st[(((size_t)(b * 8 + h)) << 12) + (c << 6) + tid];
    tq[tid] = t;
    tk[tid] = t;
  } else if (tid < 128) {
    int j = tid - 64;
    tk[64 + j] = st[(((size_t)(b * 8 + hp)) << 12) + (cp << 6) + j];
  }
  __syncthreads();
  for (int idx = tid; idx < 512; idx += 256) {
    int row = idx >> 3, fo = idx & 7;
    half8 val = *(const half8*)(qh + (((size_t)(b << 12) + tq[row]) << 6) + fo * 8);
    *(half4*)(Qs + row * 68 + fo * 8) = __builtin_shufflevector(val, val, 0, 1, 2, 3);
    *(half4*)(Qs + row * 68 + fo * 8 + 4) = __builtin_shufflevector(val, val, 4, 5, 6, 7);
  }
  for (int idx = tid; idx < 1024; idx += 256) {
    int row = idx >> 3, fo = idx & 7;
    half8 val = *(const half8*)(khat + (((size_t)(b << 12) + tk[row]) << 6) + fo * 8);
    *(half4*)(Ks + row * 68 + fo * 8) = __builtin_shufflevector(val, val, 0, 1, 2, 3);
    *(half4*)(Ks + row * 68 + fo * 8 + 4) = __builtin_shufflevector(val, val, 4, 5, 6, 7);
  }
  __syncthreads();

  int lane = tid & 63, w = tid >> 6;
  int m = lane & 15, quad = lane >> 4;
  half8 afr[2];
#pragma unroll
  for (int ki = 0; ki < 2; ki++) {
    const half_t* ap = Qs + (w * 16 + m) * 68 + ki * 32 + quad * 8;
    half4 lo = *(const half4*)ap, hi = *(const half4*)(ap + 4);
    afr[ki] = __builtin_shufflevector(lo, hi, 0, 1, 2, 3, 4, 5, 6, 7);
  }
  int ti[4];
#pragma unroll
  for (int r = 0; r < 4; r++) ti[r] = tq[w * 16 + quad * 4 + r];

  float d[8][4];
#pragma unroll
  for (int nt = 0; nt < 8; nt++) {
    floatx4 acc = {0.f, 0.f, 0.f, 0.f};
#pragma unroll
    for (int ki = 0; ki < 2; ki++) {
      const half_t* bp = Ks + (nt * 16 + m) * 68 + ki * 32 + quad * 8;
      half4 lo = *(const half4*)bp, hi = *(const half4*)(bp + 4);
      half8 bfr = __builtin_shufflevector(lo, hi, 0, 1, 2, 3, 4, 5, 6, 7);
      acc = __builtin_amdgcn_mfma_f32_16x16x32_f16(afr[ki], bfr, acc, 0, 0, 0);
    }
    int tj = tk[nt * 16 + m];
#pragma unroll
    for (int r = 0; r < 4; r++)
      d[nt][r] = (ti[r] == tj) ? -50000.0f : acc[r] * 0.125f;
  }

#pragma unroll
  for (int r = 0; r < 4; r++) {
    float mr = d[0][r];
#pragma unroll
    for (int nt = 1; nt < 8; nt++) mr = fmaxf(mr, d[nt][r]);
    for (int off = 1; off < 16; off <<= 1) mr = fmaxf(mr, __shfl_xor(mr, off));
    float lr = 0.f;
#pragma unroll
    for (int nt = 0; nt < 8; nt++) lr += expf(d[nt][r] - mr);
    for (int off = 1; off < 16; off <<= 1) lr += __shfl_xor(lr, off);
    if (m == 0) lse[(((size_t)(b * 8 + h)) << 12) + ti[r]] = mr + logf(lr);
  }
}

// ---------------- Kernel 4: logsumexp across hash rounds ----------------
__global__ __launch_bounds__(256) void lsetot_kernel(const float* __restrict__ lse,
                                                     float* __restrict__ lset) {
  int idx = blockIdx.x * 256 + threadIdx.x;  // over B*S
  int b = idx >> 12, t = idx & 4095;
  float vals[8];
  float m = -3.4e38f;
#pragma unroll
  for (int hh = 0; hh < 8; hh++) {
    vals[hh] = lse[(((size_t)(b * 8 + hh)) << 12) + t];
    m = fmaxf(m, vals[hh]);
  }
  float ssum = 0.f;
#pragma unroll
  for (int hh = 0; hh < 8; hh++) ssum += expf(vals[hh] - m);
  lset[idx] = m + logf(ssum);
}

// ---------------- Kernel 5: pass B — weighted PV (MFMA), scatter-add ----------------
// grid: B*512 blocks, 256 threads = 4 waves
__global__ __launch_bounds__(256) void passB_kernel(const half_t* __restrict__ qh,
                                                    const half_t* __restrict__ khat,
                                                    const half_t* __restrict__ vh,
                                                    const int* __restrict__ st,
                                                    const float* __restrict__ lset,
                                                    float* __restrict__ out) {
  __shared__ half_t Ks[128 * 68];
  __shared__ half_t Vt[64 * 132];   // V transposed: [dim][key]
  __shared__ half_t PQ[64 * 132];   // union: Qs (stride 68), then Ps (stride 132)
  __shared__ int tq[64];
  __shared__ int tk[128];
  __shared__ float lsetS[64];
  int tid = threadIdx.x;
  int g = blockIdx.x & 511;
  int b = blockIdx.x >> 9;
  int h = g >> 6, c = g & 63;
  int gp = (g + 511) & 511;
  int hp = gp >> 6, cp = gp & 63;
  if (tid < 64) {
    int t = st[(((size_t)(b * 8 + h)) << 12) + (c << 6) + tid];
    tq[tid] = t;
    tk[tid] = t;
  } else if (tid < 128) {
    int j = tid - 64;
    tk[64 + j] = st[(((size_t)(b * 8 + hp)) << 12) + (cp << 6) + j];
  }
  __syncthreads();
  if (tid < 64) lsetS[tid] = lset[(b << 12) + tq[tid]];
  // stage Q (stride 68, into PQ)
  for (int idx = tid; idx < 512; idx += 256) {
    int row = idx >> 3, fo = idx & 7;
    half8 val = *(const half8*)(qh + (((size_t)(b << 12) + tq[row]) << 6) + fo * 8);
    *(half4*)(PQ + row * 68 + fo * 8) = __builtin_shufflevector(val, val, 0, 1, 2, 3);
    *(half4*)(PQ + row * 68 + fo * 8 + 4) = __builtin_shufflevector(val, val, 4, 5, 6, 7);
  }
  // stage K
  for (int idx = tid; idx < 1024; idx += 256) {
    int row = idx >> 3, fo = idx & 7;
    half8 val = *(const half8*)(khat + (((size_t)(b << 12) + tk[row]) << 6) + fo * 8);
    *(half4*)(Ks + row * 68 + fo * 8) = __builtin_shufflevector(val, val, 0, 1, 2, 3);
    *(half4*)(Ks + row * 68 + fo * 8 + 4) = __builtin_shufflevector(val, val, 4, 5, 6, 7);
  }
  // stage V transposed (pack key-pairs into dwords)
  for (int idx = tid; idx < 512; idx += 256) {
    int kp = idx & 63, ch = idx >> 6;  // dims ch*8..ch*8+7
    half8 r0 = *(const half8*)(vh + (((size_t)(b << 12) + tk[2 * kp]) << 6) + ch * 8);
    half8 r1 = *(const half8*)(vh + (((size_t)(b << 12) + tk[2 * kp + 1]) << 6) + ch * 8);
#pragma unroll
    for (int j = 0; j < 8; j++) {
      half2t pr = {r0[j], r1[j]};
      *(half2t*)(Vt + (ch * 8 + j) * 132 + 2 * kp) = pr;
    }
  }
  __syncthreads();

  int lane = tid & 63, w = tid >> 6;
  int m = lane & 15, quad = lane >> 4;
  half8 afr[2];
#pragma unroll
  for (int ki = 0; ki < 2; ki++) {
    const half_t* ap = PQ + (w * 16 + m) * 68 + ki * 32 + quad * 8;
    half4 lo = *(const half4*)ap, hi = *(const half4*)(ap + 4);
    afr[ki] = __builtin_shufflevector(lo, hi, 0, 1, 2, 3, 4, 5, 6, 7);
  }
  int ti[4];
  float Lr[4];
#pragma unroll
  for (int r = 0; r < 4; r++) {
    ti[r] = tq[w * 16 + quad * 4 + r];
    Lr[r] = lsetS[w * 16 + quad * 4 + r];
  }

  float d[8][4];
#pragma unroll
  for (int nt = 0; nt < 8; nt++) {
    floatx4 acc = {0.f, 0.f, 0.f, 0.f};
#pragma unroll
    for (int ki = 0; ki < 2; ki++) {
      const half_t* bp = Ks + (nt * 16 + m) * 68 + ki * 32 + quad * 8;
      half4 lo = *(const half4*)bp, hi = *(const half4*)(bp + 4);
      half8 bfr = __builtin_shufflevector(lo, hi, 0, 1, 2, 3, 4, 5, 6, 7);
      acc = __builtin_amdgcn_mfma_f32_16x16x32_f16(afr[ki], bfr, acc, 0, 0, 0);
    }
#pragma unroll
    for (int r = 0; r < 4; r++) d[nt][r] = acc[r];
  }
  __syncthreads();  // all waves done reading PQ-as-Qs

  // P = exp(d*scale - LSE_tot), masked; write fp16 to PQ (stride 132)
#pragma unroll
  for (int nt = 0; nt < 8; nt++) {
    int tj = tk[nt * 16 + m];
#pragma unroll
    for (int r = 0; r < 4; r++) {
      float p = (ti[r] == tj) ? 0.f : expf(d[nt][r] * 0.125f - Lr[r]);
      PQ[(w * 16 + quad * 4 + r) * 132 + nt * 16 + m] = (half_t)p;
    }
  }
  __syncthreads();

  // PV: A = P rows (w-tile), B = Vt
  half8 pfr[4];
#pragma unroll
  for (int kk = 0; kk < 4; kk++) {
    const half_t* ap = PQ + (w * 16 + m) * 132 + kk * 32 + quad * 8;
    half4 lo = *(const half4*)ap, hi = *(const half4*)(ap + 4);
    pfr[kk] = __builtin_shufflevector(lo, hi, 0, 1, 2, 3, 4, 5, 6, 7);
  }
#pragma unroll
  for (int dt = 0; dt < 4; dt++) {
    floatx4 acc = {0.f, 0.f, 0.f, 0.f};
#pragma unroll
    for (int kk = 0; kk < 4; kk++) {
      const half_t* bp = Vt + (dt * 16 + m) * 132 + kk * 32 + quad * 8;
      half4 lo = *(const half4*)bp, hi = *(const half4*)(bp + 4);
      half8 bfr = __builtin_shufflevector(lo, hi, 0, 1, 2, 3, 4, 5, 6, 7);
      acc = __builtin_amdgcn_mfma_f32_16x16x32_f16(pfr[kk], bfr, acc, 0, 0, 0);
    }
#pragma unroll
    for (int r = 0; r < 4; r++) {
      unsafeAtomicAdd(out + ((((size_t)(b << 12)) + ti[r]) << 6) + dt * 16 + m, acc[r]);
    }
  }
}

extern "C" void kernel_launch(void* const* d_in, const int* in_sizes, int n_in,
                              void* d_out, int out_size, void* d_ws, size_t ws_size,
                              hipStream_t stream) {
  const float* qk = (const float*)d_in[0];
  const float* v = (const float*)d_in[1];
  const float* rot = (const float*)d_in[2];
  float* out = (float*)d_out;

  int* bkt = (int*)d_ws;                            // B*H*S ints (2MB)
  int* stp = bkt + NB_B * NB_H * NB_S;              // 2MB
  float* lse = (float*)(stp + NB_B * NB_H * NB_S);  // 2MB
  float* lset = lse + NB_B * NB_H * NB_S;           // B*S floats (256KB)
  half_t* qh = (half_t*)(lset + NB_B * NB_S);       // B*S*D halfs (8MB)
  half_t* khat = qh + (size_t)NB_B * NB_S * NB_D;   // 8MB
  half_t* vh = khat + (size_t)NB_B * NB_S * NB_D;   // 8MB

  hipMemsetAsync(d_out, 0, (size_t)out_size * sizeof(float), stream);
  prep_kernel<<<NB_B * NB_S * 16 / 256, 256, 0, stream>>>(qk, v, qh, khat, vh);
  hash_kernel<<<NB_B * NB_H * 16, 256, 0, stream>>>(qk, rot, bkt);
  sort_kernel<<<NB_B * NB_H, 256, 0, stream>>>(bkt, stp);
  passA_kernel<<<NB_B * 512, 256, 0, stream>>>(qh, khat, stp, lse);
  lsetot_kernel<<<NB_B * NB_S / 256, 256, 0, stream>>>(lse, lset);
  passB_kernel<<<NB_B * 512, 256, 0, stream>>>(qh, khat, vh, stp, lset, out);
}

// Round 4
// 302.903 us; speedup vs baseline: 2.8321x; 1.1157x over previous
//
#include <hip/hip_runtime.h>
#include <math.h>

#define NB_B 16
#define NB_S 4096
#define NB_D 64
#define NB_H 8

typedef _Float16 half_t;
typedef __attribute__((ext_vector_type(2))) _Float16 half2t;
typedef __attribute__((ext_vector_type(4))) _Float16 half4;
typedef __attribute__((ext_vector_type(8))) _Float16 half8;
typedef __attribute__((ext_vector_type(4))) float floatx4;

// ---------------- Kernel 0: precompute fp16 k-hat, v, f32 norm ----------------
// grid: B*S*16/256 blocks; 16 lanes per row. q = norm * khat (Q never stored).
__global__ __launch_bounds__(256) void prep_kernel(const float* __restrict__ qk,
                                                   const float* __restrict__ v,
                                                   half_t* __restrict__ khat,
                                                   half_t* __restrict__ vh,
                                                   float* __restrict__ norm) {
  int g = blockIdx.x * 256 + threadIdx.x;  // over B*S*16
  float4 qv = ((const float4*)qk)[g];
  float4 vv = ((const float4*)v)[g];
  float ss = qv.x * qv.x + qv.y * qv.y + qv.z * qv.z + qv.w * qv.w;
  for (int off = 1; off < 16; off <<= 1) ss += __shfl_xor(ss, off);
  float nr = fmaxf(sqrtf(ss), 1e-12f);
  float sc = 1.0f / nr;
  half4 hk = {(half_t)(qv.x * sc), (half_t)(qv.y * sc), (half_t)(qv.z * sc),
              (half_t)(qv.w * sc)};
  half4 hv = {(half_t)vv.x, (half_t)vv.y, (half_t)vv.z, (half_t)vv.w};
  ((half4*)khat)[g] = hk;
  ((half4*)vh)[g] = hv;
  if ((threadIdx.x & 15) == 0) norm[g >> 4] = nr;
}

// ---------------- Kernel 1: LSH hashing (buckets) ----------------
// Bit-faithful mimic of naive np.einsum float32 (keeps bucket decisions
// identical to the harness reference). One thread per token.
__global__ __launch_bounds__(256) void hash_kernel(const float* __restrict__ qk,
                                                   const float* __restrict__ rot,
                                                   int* __restrict__ bkt) {
  __shared__ float rotS[64 * 32];  // [f][i]
  int tid = threadIdx.x;
  int blk = blockIdx.x;
  int tile = blk & 15, bh = blk >> 4;
  int h = bh & 7, b = bh >> 3;
  int t = (tile << 8) + tid;

  for (int i = tid; i < 2048; i += 256) {
    int f = i >> 5, ii = i & 31;
    rotS[i] = rot[(((size_t)b * 64 + f) * 8 + h) * 32 + ii];
  }
  __syncthreads();

  const float4* qrow = (const float4*)(qk + (((size_t)b << 12) + t) * 64);
  float qreg[64];
#pragma unroll
  for (int j = 0; j < 16; j++) *(float4*)(qreg + 4 * j) = qrow[j];

  float acc[32];
#pragma unroll
  for (int i = 0; i < 32; i++) acc[i] = 0.f;

#pragma unroll
  for (int f = 0; f < 64; f++) {
    float qf = qreg[f];
#pragma unroll
    for (int i4 = 0; i4 < 8; i4++) {
      float4 w = *(const float4*)(rotS + f * 32 + i4 * 4);
      acc[i4 * 4 + 0] = __fadd_rn(acc[i4 * 4 + 0], __fmul_rn(qf, w.x));
      acc[i4 * 4 + 1] = __fadd_rn(acc[i4 * 4 + 1], __fmul_rn(qf, w.y));
      acc[i4 * 4 + 2] = __fadd_rn(acc[i4 * 4 + 2], __fmul_rn(qf, w.z));
      acc[i4 * 4 + 3] = __fadd_rn(acc[i4 * 4 + 3], __fmul_rn(qf, w.w));
    }
  }

  float b1 = acc[0];
  int i1 = 0;
#pragma unroll
  for (int i = 1; i < 32; i++)
    if (acc[i] > b1) { b1 = acc[i]; i1 = i; }
#pragma unroll
  for (int i = 0; i < 32; i++) {
    float x = -acc[i];
    if (x > b1) { b1 = x; i1 = 32 + i; }
  }
  bkt[(((size_t)(b * 8 + h)) << 12) + t] = i1;
}

// ---------------- Kernel 2: stable counting sort per (b,h) ----------------
__global__ __launch_bounds__(256) void sort_kernel(const int* __restrict__ bkt,
                                                   int* __restrict__ st) {
  __shared__ int lb[4096];
  __shared__ int hist[4096];  // [chunk(64)][bucket(64)]
  __shared__ int cumoff[64];
  __shared__ int tot[64];
  int tid = threadIdx.x;
  int b = blockIdx.x >> 3, h = blockIdx.x & 7;
  const int* gb = bkt + (((size_t)(b * 8 + h)) << 12);
  for (int t = tid; t < 4096; t += 256) lb[t] = gb[t];
  for (int i = tid; i < 4096; i += 256) hist[i] = 0;
  __syncthreads();
  for (int t = tid; t < 4096; t += 256) atomicAdd(&hist[((t >> 6) << 6) | lb[t]], 1);
  __syncthreads();
  if (tid < 64) {
    int run = 0;
    for (int cc = 0; cc < 64; cc++) {
      int x = hist[(cc << 6) | tid];
      hist[(cc << 6) | tid] = run;
      run += x;
    }
    tot[tid] = run;
  }
  __syncthreads();
  if (tid == 0) {
    int run = 0;
    for (int vb = 0; vb < 64; vb++) { cumoff[vb] = run; run += tot[vb]; }
  }
  __syncthreads();
  int lane = tid & 63;
  for (int p = 0; p < 16; p++) {
    int t = (p << 8) + tid;  // each wave covers one aligned 64-token chunk
    int vb = lb[t];
    unsigned long long m = 0xFFFFFFFFFFFFFFFFull;
#pragma unroll
    for (int bit = 0; bit < 6; bit++) {
      unsigned long long bl = __ballot((vb >> bit) & 1);
      m &= ((vb >> bit) & 1) ? bl : ~bl;
    }
    int rank = __popcll(m & ((1ull << lane) - 1ull));
    int cpos = cumoff[vb] + hist[((t >> 6) << 6) | vb] + rank;
    st[(((size_t)(b * 8 + h)) << 12) + cpos] = t;
  }
}

// ---------------- Kernel 3: pass A — per-row logsumexp (MFMA) ----------------
// grid: B*512 blocks (64q x 128k chunk), 256 threads = 4 waves.
// Only khat staged; Q rows are K rows 0..63 scaled by norm in epilogue.
__global__ __launch_bounds__(256) void passA_kernel(const half_t* __restrict__ khat,
                                                    const float* __restrict__ norm,
                                                    const int* __restrict__ st,
                                                    float* __restrict__ lse) {
  __shared__ half_t Ks[128 * 68];
  __shared__ int tk[128];
  __shared__ float normS[64];
  int tid = threadIdx.x;
  int g = blockIdx.x & 511;
  int b = blockIdx.x >> 9;
  int h = g >> 6, c = g & 63;
  int gp = (g + 511) & 511;
  int hp = gp >> 6, cp = gp & 63;
  if (tid < 64) {
    tk[tid] = st[(((size_t)(b * 8 + h)) << 12) + (c << 6) + tid];
  } else if (tid < 128) {
    tk[tid] = st[(((size_t)(b * 8 + hp)) << 12) + (cp << 6) + (tid - 64)];
  }
  __syncthreads();
  if (tid < 64) normS[tid] = norm[(b << 12) + tk[tid]];
  for (int idx = tid; idx < 1024; idx += 256) {
    int row = idx >> 3, fo = idx & 7;
    half8 val = *(const half8*)(khat + (((size_t)(b << 12) + tk[row]) << 6) + fo * 8);
    *(half4*)(Ks + row * 68 + fo * 8) = __builtin_shufflevector(val, val, 0, 1, 2, 3);
    *(half4*)(Ks + row * 68 + fo * 8 + 4) = __builtin_shufflevector(val, val, 4, 5, 6, 7);
  }
  __syncthreads();

  int lane = tid & 63, w = tid >> 6;
  int m = lane & 15, quad = lane >> 4;
  half8 afr[2];
#pragma unroll
  for (int ki = 0; ki < 2; ki++) {
    const half_t* ap = Ks + (w * 16 + m) * 68 + ki * 32 + quad * 8;
    half4 lo = *(const half4*)ap, hi = *(const half4*)(ap + 4);
    afr[ki] = __builtin_shufflevector(lo, hi, 0, 1, 2, 3, 4, 5, 6, 7);
  }
  int ti[4];
  float scr[4];
#pragma unroll
  for (int r = 0; r < 4; r++) {
    ti[r] = tk[w * 16 + quad * 4 + r];
    scr[r] = 0.125f * normS[w * 16 + quad * 4 + r];
  }

  float d[8][4];
#pragma unroll
  for (int nt = 0; nt < 8; nt++) {
    floatx4 acc = {0.f, 0.f, 0.f, 0.f};
#pragma unroll
    for (int ki = 0; ki < 2; ki++) {
      const half_t* bp = Ks + (nt * 16 + m) * 68 + ki * 32 + quad * 8;
      half4 lo = *(const half4*)bp, hi = *(const half4*)(bp + 4);
      half8 bfr = __builtin_shufflevector(lo, hi, 0, 1, 2, 3, 4, 5, 6, 7);
      acc = __builtin_amdgcn_mfma_f32_16x16x32_f16(afr[ki], bfr, acc, 0, 0, 0);
    }
    int tj = tk[nt * 16 + m];
#pragma unroll
    for (int r = 0; r < 4; r++)
      d[nt][r] = (ti[r] == tj) ? -50000.0f : acc[r] * scr[r];
  }

#pragma unroll
  for (int r = 0; r < 4; r++) {
    float mr = d[0][r];
#pragma unroll
    for (int nt = 1; nt < 8; nt++) mr = fmaxf(mr, d[nt][r]);
    for (int off = 1; off < 16; off <<= 1) mr = fmaxf(mr, __shfl_xor(mr, off));
    float lr = 0.f;
#pragma unroll
    for (int nt = 0; nt < 8; nt++) lr += __expf(d[nt][r] - mr);
    for (int off = 1; off < 16; off <<= 1) lr += __shfl_xor(lr, off);
    if (m == 0) lse[(((size_t)(b * 8 + h)) << 12) + ti[r]] = mr + __logf(lr);
  }
}

// ---------------- Kernel 4: logsumexp across hash rounds ----------------
__global__ __launch_bounds__(256) void lsetot_kernel(const float* __restrict__ lse,
                                                     float* __restrict__ lset) {
  int idx = blockIdx.x * 256 + threadIdx.x;  // over B*S
  int b = idx >> 12, t = idx & 4095;
  float vals[8];
  float m = -3.4e38f;
#pragma unroll
  for (int hh = 0; hh < 8; hh++) {
    vals[hh] = lse[(((size_t)(b * 8 + hh)) << 12) + t];
    m = fmaxf(m, vals[hh]);
  }
  float ssum = 0.f;
#pragma unroll
  for (int hh = 0; hh < 8; hh++) ssum += __expf(vals[hh] - m);
  lset[idx] = m + __logf(ssum);
}

// ---------------- Kernel 5: pass B — weighted PV (MFMA), scatter-add ----------------
// grid: B*512 blocks, 256 threads = 4 waves. LDS ~28KB -> 5 blocks/CU.
// K tile reused for P after dots; V staged in two 64-key halves.
__global__ __launch_bounds__(256) void passB_kernel(const half_t* __restrict__ khat,
                                                    const half_t* __restrict__ vh,
                                                    const float* __restrict__ norm,
                                                    const int* __restrict__ st,
                                                    const float* __restrict__ lset,
                                                    float* __restrict__ out) {
  __shared__ half_t Ks[128 * 68];  // K (stride 68); later P (64 rows, stride 132)
  __shared__ half_t Vt[64 * 68];   // one 64-key half of V^T: [dim][key]
  __shared__ int tk[128];
  __shared__ float normS[64];
  __shared__ float lsetS[64];
  int tid = threadIdx.x;
  int g = blockIdx.x & 511;
  int b = blockIdx.x >> 9;
  int h = g >> 6, c = g & 63;
  int gp = (g + 511) & 511;
  int hp = gp >> 6, cp = gp & 63;
  if (tid < 64) {
    tk[tid] = st[(((size_t)(b * 8 + h)) << 12) + (c << 6) + tid];
  } else if (tid < 128) {
    tk[tid] = st[(((size_t)(b * 8 + hp)) << 12) + (cp << 6) + (tid - 64)];
  }
  __syncthreads();
  if (tid < 64) {
    int t = tk[tid];
    normS[tid] = norm[(b << 12) + t];
    lsetS[tid] = lset[(b << 12) + t];
  }
  // stage K (128 rows, stride 68)
  for (int idx = tid; idx < 1024; idx += 256) {
    int row = idx >> 3, fo = idx & 7;
    half8 val = *(const half8*)(khat + (((size_t)(b << 12) + tk[row]) << 6) + fo * 8);
    *(half4*)(Ks + row * 68 + fo * 8) = __builtin_shufflevector(val, val, 0, 1, 2, 3);
    *(half4*)(Ks + row * 68 + fo * 8 + 4) = __builtin_shufflevector(val, val, 4, 5, 6, 7);
  }
  // stage V half 0 (keys 0..63) transposed
  {
    int kp = tid & 31, ch = tid >> 5;  // ch in 0..7
    half8 r0 = *(const half8*)(vh + (((size_t)(b << 12) + tk[2 * kp]) << 6) + ch * 8);
    half8 r1 = *(const half8*)(vh + (((size_t)(b << 12) + tk[2 * kp + 1]) << 6) + ch * 8);
#pragma unroll
    for (int j = 0; j < 8; j++) {
      half2t pr = {r0[j], r1[j]};
      *(half2t*)(Vt + (ch * 8 + j) * 68 + 2 * kp) = pr;
    }
  }
  __syncthreads();

  int lane = tid & 63, w = tid >> 6;
  int m = lane & 15, quad = lane >> 4;
  half8 afr[2];
#pragma unroll
  for (int ki = 0; ki < 2; ki++) {
    const half_t* ap = Ks + (w * 16 + m) * 68 + ki * 32 + quad * 8;
    half4 lo = *(const half4*)ap, hi = *(const half4*)(ap + 4);
    afr[ki] = __builtin_shufflevector(lo, hi, 0, 1, 2, 3, 4, 5, 6, 7);
  }
  int ti[4];
  float Lr[4], scr[4];
#pragma unroll
  for (int r = 0; r < 4; r++) {
    int rr = w * 16 + quad * 4 + r;
    ti[r] = tk[rr];
    Lr[r] = lsetS[rr];
    scr[r] = 0.125f * normS[rr];
  }

  float d[8][4];
#pragma unroll
  for (int nt = 0; nt < 8; nt++) {
    floatx4 acc = {0.f, 0.f, 0.f, 0.f};
#pragma unroll
    for (int ki = 0; ki < 2; ki++) {
      const half_t* bp = Ks + (nt * 16 + m) * 68 + ki * 32 + quad * 8;
      half4 lo = *(const half4*)bp, hi = *(const half4*)(bp + 4);
      half8 bfr = __builtin_shufflevector(lo, hi, 0, 1, 2, 3, 4, 5, 6, 7);
      acc = __builtin_amdgcn_mfma_f32_16x16x32_f16(afr[ki], bfr, acc, 0, 0, 0);
    }
#pragma unroll
    for (int r = 0; r < 4; r++) d[nt][r] = acc[r];
  }
  __syncthreads();  // all waves done reading Ks as K

  // P = exp(d*scale - LSE_tot), masked; fp16 into Ks region (stride 132)
  half_t* Ps = Ks;
#pragma unroll
  for (int nt = 0; nt < 8; nt++) {
    int tj = tk[nt * 16 + m];
#pragma unroll
    for (int r = 0; r < 4; r++) {
      float p = (ti[r] == tj) ? 0.f : __expf(d[nt][r] * scr[r] - Lr[r]);
      Ps[(w * 16 + quad * 4 + r) * 132 + nt * 16 + m] = (half_t)p;
    }
  }
  __syncthreads();

  half8 pfr[4];
#pragma unroll
  for (int kk = 0; kk < 4; kk++) {
    const half_t* ap = Ps + (w * 16 + m) * 132 + kk * 32 + quad * 8;
    half4 lo = *(const half4*)ap, hi = *(const half4*)(ap + 4);
    pfr[kk] = __builtin_shufflevector(lo, hi, 0, 1, 2, 3, 4, 5, 6, 7);
  }

  floatx4 accO[4];
#pragma unroll
  for (int dt = 0; dt < 4; dt++) accO[dt] = (floatx4){0.f, 0.f, 0.f, 0.f};

  // PV with V half 0 (keys 0..63 -> pfr 0,1)
#pragma unroll
  for (int dt = 0; dt < 4; dt++) {
#pragma unroll
    for (int kk = 0; kk < 2; kk++) {
      const half_t* bp = Vt + (dt * 16 + m) * 68 + kk * 32 + quad * 8;
      half4 lo = *(const half4*)bp, hi = *(const half4*)(bp + 4);
      half8 bfr = __builtin_shufflevector(lo, hi, 0, 1, 2, 3, 4, 5, 6, 7);
      accO[dt] = __builtin_amdgcn_mfma_f32_16x16x32_f16(pfr[kk], bfr, accO[dt], 0, 0, 0);
    }
  }
  __syncthreads();  // V half 0 reads done

  // stage V half 1 (keys 64..127)
  {
    int kp = tid & 31, ch = tid >> 5;
    half8 r0 = *(const half8*)(vh + (((size_t)(b << 12) + tk[64 + 2 * kp]) << 6) + ch * 8);
    half8 r1 = *(const half8*)(vh + (((size_t)(b << 12) + tk[65 + 2 * kp]) << 6) + ch * 8);
#pragma unroll
    for (int j = 0; j < 8; j++) {
      half2t pr = {r0[j], r1[j]};
      *(half2t*)(Vt + (ch * 8 + j) * 68 + 2 * kp) = pr;
    }
  }
  __syncthreads();

  // PV with V half 1 (keys 64..127 -> pfr 2,3)
#pragma unroll
  for (int dt = 0; dt < 4; dt++) {
#pragma unroll
    for (int kk = 2; kk < 4; kk++) {
      const half_t* bp = Vt + (dt * 16 + m) * 68 + (kk - 2) * 32 + quad * 8;
      half4 lo = *(const half4*)bp, hi = *(const half4*)(bp + 4);
      half8 bfr = __builtin_shufflevector(lo, hi, 0, 1, 2, 3, 4, 5, 6, 7);
      accO[dt] = __builtin_amdgcn_mfma_f32_16x16x32_f16(pfr[kk], bfr, accO[dt], 0, 0, 0);
    }
  }

#pragma unroll
  for (int dt = 0; dt < 4; dt++) {
#pragma unroll
    for (int r = 0; r < 4; r++) {
      unsafeAtomicAdd(out + ((((size_t)(b << 12)) + ti[r]) << 6) + dt * 16 + m,
                      accO[dt][r]);
    }
  }
}

extern "C" void kernel_launch(void* const* d_in, const int* in_sizes, int n_in,
                              void* d_out, int out_size, void* d_ws, size_t ws_size,
                              hipStream_t stream) {
  const float* qk = (const float*)d_in[0];
  const float* v = (const float*)d_in[1];
  const float* rot = (const float*)d_in[2];
  float* out = (float*)d_out;

  int* bkt = (int*)d_ws;                            // 2MB
  int* stp = bkt + NB_B * NB_H * NB_S;              // 2MB
  float* lse = (float*)(stp + NB_B * NB_H * NB_S);  // 2MB
  float* lset = lse + NB_B * NB_H * NB_S;           // 256KB
  float* norm = lset + NB_B * NB_S;                 // 256KB
  half_t* khat = (half_t*)(norm + NB_B * NB_S);     // 8MB
  half_t* vh = khat + (size_t)NB_B * NB_S * NB_D;   // 8MB

  hipMemsetAsync(d_out, 0, (size_t)out_size * sizeof(float), stream);
  prep_kernel<<<NB_B * NB_S * 16 / 256, 256, 0, stream>>>(qk, v, khat, vh, norm);
  hash_kernel<<<NB_B * NB_H * 16, 256, 0, stream>>>(qk, rot, bkt);
  sort_kernel<<<NB_B * NB_H, 256, 0, stream>>>(bkt, stp);
  passA_kernel<<<NB_B * 512, 256, 0, stream>>>(khat, norm, stp, lse);
  lsetot_kernel<<<NB_B * NB_S / 256, 256, 0, stream>>>(lse, lset);
  passB_kernel<<<NB_B * 512, 256, 0, stream>>>(khat, vh, norm, stp, lset, out);
}

// Round 5
// 217.255 us; speedup vs baseline: 3.9485x; 1.3942x over previous
//
#include <hip/hip_runtime.h>
#include <math.h>

#define NB_B 16
#define NB_S 4096
#define NB_D 64
#define NB_H 8

typedef _Float16 half_t;
typedef __attribute__((ext_vector_type(2))) _Float16 half2t;
typedef __attribute__((ext_vector_type(4))) _Float16 half4;
typedef __attribute__((ext_vector_type(8))) _Float16 half8;
typedef __attribute__((ext_vector_type(4))) float floatx4;

// ---------------- Kernel 0: precompute fp16 k-hat, v, f32 norm ----------------
// grid: B*S*16/256 blocks; 16 lanes per row. q = norm * khat (Q never stored).
__global__ __launch_bounds__(256) void prep_kernel(const float* __restrict__ qk,
                                                   const float* __restrict__ v,
                                                   half_t* __restrict__ khat,
                                                   half_t* __restrict__ vh,
                                                   float* __restrict__ norm) {
  int g = blockIdx.x * 256 + threadIdx.x;  // over B*S*16
  float4 qv = ((const float4*)qk)[g];
  float4 vv = ((const float4*)v)[g];
  float ss = qv.x * qv.x + qv.y * qv.y + qv.z * qv.z + qv.w * qv.w;
  for (int off = 1; off < 16; off <<= 1) ss += __shfl_xor(ss, off);
  float nr = fmaxf(sqrtf(ss), 1e-12f);
  float sc = 1.0f / nr;
  half4 hk = {(half_t)(qv.x * sc), (half_t)(qv.y * sc), (half_t)(qv.z * sc),
              (half_t)(qv.w * sc)};
  half4 hv = {(half_t)vv.x, (half_t)vv.y, (half_t)vv.z, (half_t)vv.w};
  ((half4*)khat)[g] = hk;
  ((half4*)vh)[g] = hv;
  if ((threadIdx.x & 15) == 0) norm[g >> 4] = nr;
}

// ---------------- Kernel 1: LSH hashing (buckets) ----------------
// Bit-faithful mimic of naive np.einsum float32 (keeps bucket decisions
// identical to the harness reference). One thread per token.
__global__ __launch_bounds__(256) void hash_kernel(const float* __restrict__ qk,
                                                   const float* __restrict__ rot,
                                                   int* __restrict__ bkt) {
  __shared__ float rotS[64 * 32];  // [f][i]
  int tid = threadIdx.x;
  int blk = blockIdx.x;
  int tile = blk & 15, bh = blk >> 4;
  int h = bh & 7, b = bh >> 3;
  int t = (tile << 8) + tid;

  for (int i = tid; i < 2048; i += 256) {
    int f = i >> 5, ii = i & 31;
    rotS[i] = rot[(((size_t)b * 64 + f) * 8 + h) * 32 + ii];
  }
  __syncthreads();

  const float4* qrow = (const float4*)(qk + (((size_t)b << 12) + t) * 64);
  float qreg[64];
#pragma unroll
  for (int j = 0; j < 16; j++) *(float4*)(qreg + 4 * j) = qrow[j];

  float acc[32];
#pragma unroll
  for (int i = 0; i < 32; i++) acc[i] = 0.f;

#pragma unroll
  for (int f = 0; f < 64; f++) {
    float qf = qreg[f];
#pragma unroll
    for (int i4 = 0; i4 < 8; i4++) {
      float4 w = *(const float4*)(rotS + f * 32 + i4 * 4);
      acc[i4 * 4 + 0] = __fadd_rn(acc[i4 * 4 + 0], __fmul_rn(qf, w.x));
      acc[i4 * 4 + 1] = __fadd_rn(acc[i4 * 4 + 1], __fmul_rn(qf, w.y));
      acc[i4 * 4 + 2] = __fadd_rn(acc[i4 * 4 + 2], __fmul_rn(qf, w.z));
      acc[i4 * 4 + 3] = __fadd_rn(acc[i4 * 4 + 3], __fmul_rn(qf, w.w));
    }
  }

  float b1 = acc[0];
  int i1 = 0;
#pragma unroll
  for (int i = 1; i < 32; i++)
    if (acc[i] > b1) { b1 = acc[i]; i1 = i; }
#pragma unroll
  for (int i = 0; i < 32; i++) {
    float x = -acc[i];
    if (x > b1) { b1 = x; i1 = 32 + i; }
  }
  bkt[(((size_t)(b * 8 + h)) << 12) + t] = i1;
}

// ---------------- Kernel 2: stable counting sort per (b,h) ----------------
__global__ __launch_bounds__(256) void sort_kernel(const int* __restrict__ bkt,
                                                   int* __restrict__ st) {
  __shared__ int lb[4096];
  __shared__ int hist[4096];  // [chunk(64)][bucket(64)]
  __shared__ int cumoff[64];
  __shared__ int tot[64];
  int tid = threadIdx.x;
  int b = blockIdx.x >> 3, h = blockIdx.x & 7;
  const int* gb = bkt + (((size_t)(b * 8 + h)) << 12);
  for (int t = tid; t < 4096; t += 256) lb[t] = gb[t];
  for (int i = tid; i < 4096; i += 256) hist[i] = 0;
  __syncthreads();
  for (int t = tid; t < 4096; t += 256) atomicAdd(&hist[((t >> 6) << 6) | lb[t]], 1);
  __syncthreads();
  if (tid < 64) {
    int run = 0;
    for (int cc = 0; cc < 64; cc++) {
      int x = hist[(cc << 6) | tid];
      hist[(cc << 6) | tid] = run;
      run += x;
    }
    tot[tid] = run;
  }
  __syncthreads();
  if (tid == 0) {
    int run = 0;
    for (int vb = 0; vb < 64; vb++) { cumoff[vb] = run; run += tot[vb]; }
  }
  __syncthreads();
  int lane = tid & 63;
  for (int p = 0; p < 16; p++) {
    int t = (p << 8) + tid;  // each wave covers one aligned 64-token chunk
    int vb = lb[t];
    unsigned long long m = 0xFFFFFFFFFFFFFFFFull;
#pragma unroll
    for (int bit = 0; bit < 6; bit++) {
      unsigned long long bl = __ballot((vb >> bit) & 1);
      m &= ((vb >> bit) & 1) ? bl : ~bl;
    }
    int rank = __popcll(m & ((1ull << lane) - 1ull));
    int cpos = cumoff[vb] + hist[((t >> 6) << 6) | vb] + rank;
    st[(((size_t)(b * 8 + h)) << 12) + cpos] = t;
  }
}

// ---------------- Kernel 3: fused chunk kernel ----------------
// Per (b, round, chunk): QK^T (MFMA) -> per-round softmax -> P.V (MFMA),
// write normalized per-round output o_r (fp16) + lse_r. No atomics.
// grid: B*512 blocks, 256 threads = 4 waves.
__global__ __launch_bounds__(256) void chunk_kernel(const half_t* __restrict__ khat,
                                                    const half_t* __restrict__ vh,
                                                    const float* __restrict__ norm,
                                                    const int* __restrict__ st,
                                                    half_t* __restrict__ oh,
                                                    float* __restrict__ lse) {
  __shared__ half_t Ks[128 * 68];  // K (stride 68); later P (64 rows, stride 132)
  __shared__ half_t Vt[64 * 68];   // one 64-key half of V^T: [dim][key]; later O
  __shared__ int tk[128];
  __shared__ float normS[64];
  int tid = threadIdx.x;
  int g = blockIdx.x & 511;
  int b = blockIdx.x >> 9;
  int h = g >> 6, c = g & 63;
  int gp = (g + 511) & 511;
  int hp = gp >> 6, cp = gp & 63;
  if (tid < 64) {
    tk[tid] = st[(((size_t)(b * 8 + h)) << 12) + (c << 6) + tid];
  } else if (tid < 128) {
    tk[tid] = st[(((size_t)(b * 8 + hp)) << 12) + (cp << 6) + (tid - 64)];
  }
  __syncthreads();
  if (tid < 64) normS[tid] = norm[(b << 12) + tk[tid]];
  // stage K (128 rows, stride 68)
  for (int idx = tid; idx < 1024; idx += 256) {
    int row = idx >> 3, fo = idx & 7;
    half8 val = *(const half8*)(khat + (((size_t)(b << 12) + tk[row]) << 6) + fo * 8);
    *(half4*)(Ks + row * 68 + fo * 8) = __builtin_shufflevector(val, val, 0, 1, 2, 3);
    *(half4*)(Ks + row * 68 + fo * 8 + 4) = __builtin_shufflevector(val, val, 4, 5, 6, 7);
  }
  // stage V half 0 (keys 0..63) transposed
  {
    int kp = tid & 31, ch = tid >> 5;  // ch in 0..7
    half8 r0 = *(const half8*)(vh + (((size_t)(b << 12) + tk[2 * kp]) << 6) + ch * 8);
    half8 r1 = *(const half8*)(vh + (((size_t)(b << 12) + tk[2 * kp + 1]) << 6) + ch * 8);
#pragma unroll
    for (int j = 0; j < 8; j++) {
      half2t pr = {r0[j], r1[j]};
      *(half2t*)(Vt + (ch * 8 + j) * 68 + 2 * kp) = pr;
    }
  }
  __syncthreads();

  int lane = tid & 63, w = tid >> 6;
  int m = lane & 15, quad = lane >> 4;
  half8 afr[2];
#pragma unroll
  for (int ki = 0; ki < 2; ki++) {
    const half_t* ap = Ks + (w * 16 + m) * 68 + ki * 32 + quad * 8;
    half4 lo = *(const half4*)ap, hi = *(const half4*)(ap + 4);
    afr[ki] = __builtin_shufflevector(lo, hi, 0, 1, 2, 3, 4, 5, 6, 7);
  }
  int ti[4];
  float scr[4];
#pragma unroll
  for (int r = 0; r < 4; r++) {
    int rr = w * 16 + quad * 4 + r;
    ti[r] = tk[rr];
    scr[r] = 0.125f * normS[rr];
  }

  // QK^T dots, masked + scaled
  float d[8][4];
#pragma unroll
  for (int nt = 0; nt < 8; nt++) {
    floatx4 acc = {0.f, 0.f, 0.f, 0.f};
#pragma unroll
    for (int ki = 0; ki < 2; ki++) {
      const half_t* bp = Ks + (nt * 16 + m) * 68 + ki * 32 + quad * 8;
      half4 lo = *(const half4*)bp, hi = *(const half4*)(bp + 4);
      half8 bfr = __builtin_shufflevector(lo, hi, 0, 1, 2, 3, 4, 5, 6, 7);
      acc = __builtin_amdgcn_mfma_f32_16x16x32_f16(afr[ki], bfr, acc, 0, 0, 0);
    }
    int tj = tk[nt * 16 + m];
#pragma unroll
    for (int r = 0; r < 4; r++)
      d[nt][r] = (ti[r] == tj) ? -50000.0f : acc[r] * scr[r];
  }

  // per-round row softmax stats (over the 128 keys)
  float mr[4], lr[4];
#pragma unroll
  for (int r = 0; r < 4; r++) {
    float mm = d[0][r];
#pragma unroll
    for (int nt = 1; nt < 8; nt++) mm = fmaxf(mm, d[nt][r]);
    for (int off = 1; off < 16; off <<= 1) mm = fmaxf(mm, __shfl_xor(mm, off));
    float ll = 0.f;
#pragma unroll
    for (int nt = 0; nt < 8; nt++) ll += __expf(d[nt][r] - mm);
    for (int off = 1; off < 16; off <<= 1) ll += __shfl_xor(ll, off);
    mr[r] = mm;
    lr[r] = ll;
    if (m == 0) lse[(((size_t)(b * 8 + h)) << 12) + ti[r]] = mm + __logf(ll);
  }
  __syncthreads();  // all waves done reading Ks as K

  // P' = exp(d - m_r) fp16 into Ks region (stride 132)
  half_t* Ps = Ks;
#pragma unroll
  for (int nt = 0; nt < 8; nt++) {
#pragma unroll
    for (int r = 0; r < 4; r++) {
      Ps[(w * 16 + quad * 4 + r) * 132 + nt * 16 + m] = (half_t)__expf(d[nt][r] - mr[r]);
    }
  }
  __syncthreads();

  half8 pfr[4];
#pragma unroll
  for (int kk = 0; kk < 4; kk++) {
    const half_t* ap = Ps + (w * 16 + m) * 132 + kk * 32 + quad * 8;
    half4 lo = *(const half4*)ap, hi = *(const half4*)(ap + 4);
    pfr[kk] = __builtin_shufflevector(lo, hi, 0, 1, 2, 3, 4, 5, 6, 7);
  }

  floatx4 accO[4];
#pragma unroll
  for (int dt = 0; dt < 4; dt++) accO[dt] = (floatx4){0.f, 0.f, 0.f, 0.f};

  // PV with V half 0 (keys 0..63 -> pfr 0,1)
#pragma unroll
  for (int dt = 0; dt < 4; dt++) {
#pragma unroll
    for (int kk = 0; kk < 2; kk++) {
      const half_t* bp = Vt + (dt * 16 + m) * 68 + kk * 32 + quad * 8;
      half4 lo = *(const half4*)bp, hi = *(const half4*)(bp + 4);
      half8 bfr = __builtin_shufflevector(lo, hi, 0, 1, 2, 3, 4, 5, 6, 7);
      accO[dt] = __builtin_amdgcn_mfma_f32_16x16x32_f16(pfr[kk], bfr, accO[dt], 0, 0, 0);
    }
  }
  __syncthreads();  // V half 0 reads done

  // stage V half 1 (keys 64..127)
  {
    int kp = tid & 31, ch = tid >> 5;
    half8 r0 = *(const half8*)(vh + (((size_t)(b << 12) + tk[64 + 2 * kp]) << 6) + ch * 8);
    half8 r1 = *(const half8*)(vh + (((size_t)(b << 12) + tk[65 + 2 * kp]) << 6) + ch * 8);
#pragma unroll
    for (int j = 0; j < 8; j++) {
      half2t pr = {r0[j], r1[j]};
      *(half2t*)(Vt + (ch * 8 + j) * 68 + 2 * kp) = pr;
    }
  }
  __syncthreads();

  // PV with V half 1 (keys 64..127 -> pfr 2,3)
#pragma unroll
  for (int dt = 0; dt < 4; dt++) {
#pragma unroll
    for (int kk = 2; kk < 4; kk++) {
      const half_t* bp = Vt + (dt * 16 + m) * 68 + (kk - 2) * 32 + quad * 8;
      half4 lo = *(const half4*)bp, hi = *(const half4*)(bp + 4);
      half8 bfr = __builtin_shufflevector(lo, hi, 0, 1, 2, 3, 4, 5, 6, 7);
      accO[dt] = __builtin_amdgcn_mfma_f32_16x16x32_f16(pfr[kk], bfr, accO[dt], 0, 0, 0);
    }
  }
  __syncthreads();  // PV half 1 reads of Vt done; reuse Vt for O

  // normalized O (fp16) -> LDS (stride 68), then coalesced 16B row stores
  half_t* Ot = Vt;
#pragma unroll
  for (int r = 0; r < 4; r++) {
    float inv = 1.0f / lr[r];
#pragma unroll
    for (int dt = 0; dt < 4; dt++) {
      Ot[(w * 16 + quad * 4 + r) * 68 + dt * 16 + m] = (half_t)(accO[dt][r] * inv);
    }
  }
  __syncthreads();
  for (int idx = tid; idx < 512; idx += 256) {
    int row = idx >> 3, fo = idx & 7;
    half4 lo = *(const half4*)(Ot + row * 68 + fo * 8);
    half4 hi = *(const half4*)(Ot + row * 68 + fo * 8 + 4);
    half8 val = __builtin_shufflevector(lo, hi, 0, 1, 2, 3, 4, 5, 6, 7);
    *(half8*)(oh + ((((size_t)(b * 8 + h)) << 12) + tk[row]) * 64 + fo * 8) = val;
  }
}

// ---------------- Kernel 4: combine rounds ----------------
// out[b,t,:] = sum_r exp(lse_r - lse_tot) * o_r[b,t,:]
// grid: B*S*8/256 blocks; thread = (token, 8-dim group)
__global__ __launch_bounds__(256) void combine_kernel(const half_t* __restrict__ oh,
                                                      const float* __restrict__ lse,
                                                      float* __restrict__ out) {
  int idx = blockIdx.x * 256 + threadIdx.x;  // over B*S*8
  int do8 = idx & 7;
  int ts = idx >> 3;  // b*4096 + t
  int b = ts >> 12, t = ts & 4095;
  size_t base = ((size_t)b << 15) + t;  // (b*8)<<12 + t
  float L[8];
  float m = -3.4e38f;
#pragma unroll
  for (int h = 0; h < 8; h++) {
    L[h] = lse[base + ((size_t)h << 12)];
    m = fmaxf(m, L[h]);
  }
  float s = 0.f;
#pragma unroll
  for (int h = 0; h < 8; h++) s += __expf(L[h] - m);
  float lt = m + __logf(s);
  float acc[8];
#pragma unroll
  for (int j = 0; j < 8; j++) acc[j] = 0.f;
#pragma unroll
  for (int h = 0; h < 8; h++) {
    float wgt = __expf(L[h] - lt);
    half8 o = *(const half8*)(oh + ((base + ((size_t)h << 12)) << 6) + do8 * 8);
#pragma unroll
    for (int j = 0; j < 8; j++) acc[j] += wgt * (float)o[j];
  }
  float* dst = out + ((((size_t)b << 12) + t) << 6) + do8 * 8;
  *(float4*)dst = (float4){acc[0], acc[1], acc[2], acc[3]};
  *(float4*)(dst + 4) = (float4){acc[4], acc[5], acc[6], acc[7]};
}

extern "C" void kernel_launch(void* const* d_in, const int* in_sizes, int n_in,
                              void* d_out, int out_size, void* d_ws, size_t ws_size,
                              hipStream_t stream) {
  const float* qk = (const float*)d_in[0];
  const float* v = (const float*)d_in[1];
  const float* rot = (const float*)d_in[2];
  float* out = (float*)d_out;

  int* bkt = (int*)d_ws;                            // 2MB
  int* stp = bkt + NB_B * NB_H * NB_S;              // 2MB
  float* lse = (float*)(stp + NB_B * NB_H * NB_S);  // 2MB
  float* norm = lse + NB_B * NB_H * NB_S;           // 256KB
  half_t* khat = (half_t*)(norm + NB_B * NB_S);     // 8MB
  half_t* vh = khat + (size_t)NB_B * NB_S * NB_D;   // 8MB
  half_t* oh = vh + (size_t)NB_B * NB_S * NB_D;     // B*H*S*D fp16 = 67MB

  prep_kernel<<<NB_B * NB_S * 16 / 256, 256, 0, stream>>>(qk, v, khat, vh, norm);
  hash_kernel<<<NB_B * NB_H * 16, 256, 0, stream>>>(qk, rot, bkt);
  sort_kernel<<<NB_B * NB_H, 256, 0, stream>>>(bkt, stp);
  chunk_kernel<<<NB_B * 512, 256, 0, stream>>>(khat, vh, norm, stp, oh, lse);
  combine_kernel<<<NB_B * NB_S * 8 / 256, 256, 0, stream>>>(oh, lse, out);
}